// Round 7
// baseline (187.119 us; speedup 1.0000x reference)
//
#include <hip/hip_runtime.h>
#include <hip/hip_bf16.h>
#include <math.h>

typedef unsigned short u16;
typedef __attribute__((ext_vector_type(8))) __bf16 bf16x8;
typedef __attribute__((ext_vector_type(4))) float f32x4;
typedef __attribute__((ext_vector_type(16))) float f32x16;
typedef __attribute__((ext_vector_type(8))) unsigned short u16x8;
typedef __attribute__((ext_vector_type(4))) unsigned int u32x4;
typedef __attribute__((ext_vector_type(2))) unsigned int u32x2;

// ---------- helpers ----------
__device__ __forceinline__ u16 f2bf(float f) {
  union { float f; unsigned u; } x; x.f = f;
  unsigned r = x.u + 0x7fffu + ((x.u >> 16) & 1u);   // RNE
  return (u16)(r >> 16);
}

__device__ __forceinline__ void gload16(const u16* g, u16* l) {
  __builtin_amdgcn_global_load_lds(
      (const __attribute__((address_space(1))) void*)g,
      (__attribute__((address_space(3))) void*)l, 16, 0, 0);
}

#define MFMA16(a, b, c) __builtin_amdgcn_mfma_f32_16x16x32_bf16((a), (b), (c), 0, 0, 0)
#define MFMA32(a, b, c) __builtin_amdgcn_mfma_f32_32x32x16_bf16((a), (b), (c), 0, 0, 0)

// Q pre-scale: 1/sqrt(64) * log2(e)  (softmax done in exp2 domain)
#define QSCALE 0.18033688011112043f

// ---------- cast fp32 -> bf16 (vectorized) ----------
__global__ __launch_bounds__(256) void cast_bf16_kernel(
    const float* __restrict__ in, u16* __restrict__ out, int n4) {
  int i = blockIdx.x * 256 + threadIdx.x;
  if (i >= n4) return;
  f32x4 v = *(const f32x4*)(in + (size_t)i * 4);
  u16 o0 = f2bf(v[0]), o1 = f2bf(v[1]), o2 = f2bf(v[2]), o3 = f2bf(v[3]);
  unsigned lo = (unsigned)o0 | ((unsigned)o1 << 16);
  unsigned hi = (unsigned)o2 | ((unsigned)o3 << 16);
  ((unsigned*)out)[(size_t)i * 2] = lo;
  ((unsigned*)out)[(size_t)i * 2 + 1] = hi;
}

// ---------- shared 128x128 / BK=64 bf16 GEMM main loop (C = A * B^T) ----------
__device__ __forceinline__ void gemm_bt_128(
    const u16* __restrict__ A, const u16* __restrict__ B, int K, int m0, int n0,
    u16* As, u16* Bs, f32x4 acc[4][4]) {
  const int tid = threadIdx.x;
  const int lane = tid & 63;
  const int wr = tid >> 7;
  const int wc = (tid >> 6) & 1;
  for (int k0 = 0; k0 < K; k0 += 64) {
    #pragma unroll
    for (int it = 0; it < 4; ++it) {
      int c = it * 256 + tid;
      int row = c >> 3;
      int ko = (c & 7) << 3;
      gload16(A + (size_t)(m0 + row) * K + (k0 + ko), As + c * 8);
      gload16(B + (size_t)(n0 + row) * K + (k0 + ko), Bs + c * 8);
    }
    __syncthreads();
    #pragma unroll
    for (int kk = 0; kk < 2; ++kk) {
      bf16x8 a[4], b[4];
      #pragma unroll
      for (int m = 0; m < 4; ++m)
        a[m] = *(const bf16x8*)(As + ((wr * 64 + m * 16 + (lane & 15)) * 64 +
                                      kk * 32 + ((lane >> 4) << 3)));
      #pragma unroll
      for (int n = 0; n < 4; ++n)
        b[n] = *(const bf16x8*)(Bs + ((wc * 64 + n * 16 + (lane & 15)) * 64 +
                                      kk * 32 + ((lane >> 4) << 3)));
      #pragma unroll
      for (int m = 0; m < 4; ++m)
        #pragma unroll
        for (int n = 0; n < 4; ++n)
          acc[m][n] = MFMA16(a[m], b[n], acc[m][n]);
    }
    __syncthreads();
  }
}

// ---------- GEMM1: qkv = x @ Wqkv^T + b; Q,K per-head [q][d]; V per-head [d][q] ----------
__global__ __launch_bounds__(256) void gemm_qkv_kernel(
    const u16* __restrict__ X, const u16* __restrict__ W, const float* __restrict__ bias,
    u16* __restrict__ Qb, u16* __restrict__ Kb, u16* __restrict__ VTb,
    unsigned* __restrict__ cnt) {
  if (threadIdx.x == 0 && blockIdx.x == 0 && blockIdx.y == 0) *cnt = 0u;
  __shared__ __align__(16) u16 As[128 * 64];
  __shared__ __align__(16) u16 Bs[128 * 64];
  f32x4 acc[4][4];
  #pragma unroll
  for (int m = 0; m < 4; ++m)
    #pragma unroll
    for (int n = 0; n < 4; ++n) acc[m][n] = (f32x4){0.f, 0.f, 0.f, 0.f};
  const int m0 = blockIdx.y * 128;
  const int n0 = blockIdx.x * 128;
  gemm_bt_128(X, W, 1024, m0, n0, As, Bs, acc);
  const int lane = threadIdx.x & 63;
  const int wr = threadIdx.x >> 7, wc = (threadIdx.x >> 6) & 1;
  #pragma unroll
  for (int m = 0; m < 4; ++m) {
    #pragma unroll
    for (int n = 0; n < 4; ++n) {
      #pragma unroll
      for (int j = 0; j < 4; ++j) {
        int row = m0 + wr * 64 + m * 16 + ((lane >> 4) << 2) + j;
        int col = n0 + wc * 64 + n * 16 + (lane & 15);
        float v = acc[m][n][j] + bias[col];
        int which = col >> 10;
        int rem = col & 1023;
        int h = rem >> 6, d = rem & 63;
        int bb = row >> 11, q = row & 2047;
        int hh = bb * 16 + h;
        if (which == 0) {
          Qb[((size_t)hh * 2048 + q) * 64 + d] = f2bf(v * QSCALE);
        } else if (which == 1) {
          Kb[((size_t)hh * 2048 + q) * 64 + d] = f2bf(v);
        } else {
          VTb[((size_t)hh * 64 + d) * 2048 + q] = f2bf(v);   // transposed
        }
      }
    }
  }
}

// ---------- GEMM2: out = attn @ Wo^T + b (fp32 out) ----------
__global__ __launch_bounds__(256) void gemm_out_kernel(
    const u16* __restrict__ Ain, const u16* __restrict__ W, const float* __restrict__ bias,
    float* __restrict__ out) {
  __shared__ __align__(16) u16 As[128 * 64];
  __shared__ __align__(16) u16 Bs[128 * 64];
  f32x4 acc[4][4];
  #pragma unroll
  for (int m = 0; m < 4; ++m)
    #pragma unroll
    for (int n = 0; n < 4; ++n) acc[m][n] = (f32x4){0.f, 0.f, 0.f, 0.f};
  const int m0 = blockIdx.y * 128;
  const int n0 = blockIdx.x * 128;
  gemm_bt_128(Ain, W, 1024, m0, n0, As, Bs, acc);
  const int lane = threadIdx.x & 63;
  const int wr = threadIdx.x >> 7, wc = (threadIdx.x >> 6) & 1;
  #pragma unroll
  for (int m = 0; m < 4; ++m) {
    #pragma unroll
    for (int n = 0; n < 4; ++n) {
      #pragma unroll
      for (int j = 0; j < 4; ++j) {
        int row = m0 + wr * 64 + m * 16 + ((lane >> 4) << 2) + j;
        int col = n0 + wc * 64 + n * 16 + (lane & 15);
        out[(size_t)row * 1024 + col] = acc[m][n][j] + bias[col];
      }
    }
  }
}

// ---------- causal flash attention: 32-row waves, 32x32x16 MFMA ----------
// (verified round-6 body; see comments there for fragment algebra)
__device__ __forceinline__ void attn_one(
    const u16* __restrict__ Qh, const u16* __restrict__ Kh, const u16* __restrict__ VTh,
    u16* __restrict__ Ob, int bb, int h, int qb,
    u16 (*Ks)[64 * 64], u16 (*Vt)[64 * 64]) {
  const int tid = threadIdx.x, lane = tid & 63, w = tid >> 6;
  const int half = lane >> 5, q31 = lane & 31;
  const int qrow = qb * 64 + w * 32 + q31;

  // Q fragment (B-operand): lane holds Q[qrow][dstep*16 + 8*half + i]
  bf16x8 qf[4];
  #pragma unroll
  for (int ds = 0; ds < 4; ++ds)
    qf[ds] = *(const bf16x8*)(Qh + (size_t)qrow * 64 + ds * 16 + half * 8);

  f32x16 acc_o[2] = {};
  float m_run = -INFINITY, l_run = 0.f;
  const int nt = qb + 1;

  auto stageK = [&](int t, int buf) {
    #pragma unroll
    for (int it = 0; it < 4; ++it) {
      int c = it * 128 + tid;
      int row = c >> 3, b8 = c & 7;
      gload16(Kh + (size_t)(t * 64 + row) * 64 + ((b8 ^ (row & 7)) << 3),
              Ks[buf] + c * 8);
    }
  };
  auto stageV = [&](int t, int buf) {
    #pragma unroll
    for (int it = 0; it < 4; ++it) {
      int c = it * 128 + tid;
      int d = c >> 3, b8 = c & 7;
      int fv = (d + (d >> 3)) & 7;
      gload16(VTh + (size_t)d * 2048 + t * 64 + ((b8 ^ fv) << 3),
              Vt[buf] + c * 8);
    }
  };

  stageK(0, 0);
  stageV(0, 0);
  __syncthreads();

  for (int t = 0; t < nt; ++t) {
    const int cur = t & 1;
    if (t + 1 < nt) { stageK(t + 1, cur ^ 1); stageV(t + 1, cur ^ 1); }

    // ---- ST = K @ Q^T : accs[c] = D[key = c*32 + klocal(r)][q = q31] ----
    f32x16 accs[2] = {};
    __builtin_amdgcn_s_setprio(1);
    #pragma unroll
    for (int c = 0; c < 2; ++c) {
      #pragma unroll
      for (int ds = 0; ds < 4; ++ds) {
        int row = c * 32 + q31;
        int bi = 2 * ds + half;
        bf16x8 kf = *(const bf16x8*)(Ks[cur] + row * 64 + ((bi ^ (row & 7)) << 3));
        accs[c] = MFMA32(kf, qf[ds], accs[c]);
      }
    }
    __builtin_amdgcn_s_setprio(0);

    // causal mask on diagonal tile (klocal(r) = (r&3) + 8*(r>>2) + 4*half)
    if (t == nt - 1) {
      #pragma unroll
      for (int c = 0; c < 2; ++c)
        #pragma unroll
        for (int r = 0; r < 16; ++r) {
          int kg = t * 64 + c * 32 + (r & 3) + 8 * (r >> 2) + 4 * half;
          if (kg > qrow) accs[c][r] = -INFINITY;
        }
    }

    // ---- online softmax (exp2 domain), q-row split across lane/lane+32 ----
    float mj = accs[0][0];
    #pragma unroll
    for (int c = 0; c < 2; ++c)
      #pragma unroll
      for (int r = 0; r < 16; ++r) mj = fmaxf(mj, accs[c][r]);
    mj = fmaxf(mj, __shfl_xor(mj, 32));
    float mn = fmaxf(m_run, mj);
    float sc = exp2f(m_run - mn);
    m_run = mn;
    float rs = 0.f;
    #pragma unroll
    for (int c = 0; c < 2; ++c)
      #pragma unroll
      for (int r = 0; r < 16; ++r) {
        float p = exp2f(accs[c][r] - mn);
        accs[c][r] = p;
        rs += p;
      }
    rs += __shfl_xor(rs, 32);
    l_run = l_run * sc + rs;
    acc_o[0] *= sc;
    acc_o[1] *= sc;

    // ---- pack P: Wp[c][m] = keys {(2m&3)+8*(m>>1)+4*half, +1} (+32c) ----
    unsigned Wp[2][8];
    #pragma unroll
    for (int c = 0; c < 2; ++c)
      #pragma unroll
      for (int m = 0; m < 8; ++m)
        asm("v_cvt_pk_bf16_f32 %0, %1, %2"
            : "=v"(Wp[c][m]) : "v"(accs[c][2 * m]), "v"(accs[c][2 * m + 1]));

    // ---- PV: O^T += V^T @ P, kstep k: B-frag = keys 16k + 8*half + 0..7 ----
    #pragma unroll
    for (int k = 0; k < 4; ++k) {
      const int c = k >> 1, g0 = 4 * (k & 1);
      unsigned x0 = (unsigned)__shfl_xor((int)Wp[c][g0 + 0], 32);
      unsigned x1 = (unsigned)__shfl_xor((int)Wp[c][g0 + 1], 32);
      unsigned x2 = (unsigned)__shfl_xor((int)Wp[c][g0 + 2], 32);
      unsigned x3 = (unsigned)__shfl_xor((int)Wp[c][g0 + 3], 32);
      unsigned pa0 = half ? x2 : Wp[c][g0 + 0];
      unsigned pa1 = half ? x3 : Wp[c][g0 + 1];
      unsigned pa2 = half ? Wp[c][g0 + 2] : x0;
      unsigned pa3 = half ? Wp[c][g0 + 3] : x1;
      bf16x8 pb = __builtin_bit_cast(bf16x8, (u32x4){pa0, pa1, pa2, pa3});
      __builtin_amdgcn_s_setprio(1);
      #pragma unroll
      for (int n = 0; n < 2; ++n) {
        int d = n * 32 + q31;
        int fv = (d + (d >> 3)) & 7;
        int bi = 2 * k + half;
        bf16x8 vf = *(const bf16x8*)(Vt[cur] + d * 64 + ((bi ^ fv) << 3));
        acc_o[n] = MFMA32(vf, pb, acc_o[n]);
      }
      __builtin_amdgcn_s_setprio(0);
    }
    __syncthreads();
  }

  // ---- epilogue: O^T lane-local 1/l; write bf16 rows of [B*C, H] ----
  float invl = 1.0f / l_run;
  #pragma unroll
  for (int n = 0; n < 2; ++n)
    #pragma unroll
    for (int rq = 0; rq < 4; ++rq) {
      int dbase = n * 32 + 8 * rq + 4 * half;
      u16 o0 = f2bf(acc_o[n][4 * rq + 0] * invl);
      u16 o1 = f2bf(acc_o[n][4 * rq + 1] * invl);
      u16 o2 = f2bf(acc_o[n][4 * rq + 2] * invl);
      u16 o3 = f2bf(acc_o[n][4 * rq + 3] * invl);
      unsigned lo = (unsigned)o0 | ((unsigned)o1 << 16);
      unsigned hi = (unsigned)o2 | ((unsigned)o3 << 16);
      size_t idx = ((size_t)(bb * 2048 + qrow)) * 1024 + h * 64 + dbase;
      *(u32x2*)(Ob + idx) = (u32x2){lo, hi};
    }
}

// Persistent work-stealing: 1024 units (head, qb), longest-first (LPT).
// Each 128-thread block pulls units off the global counter until exhausted.
__global__ __launch_bounds__(128) void attn_kernel(
    const u16* __restrict__ Qb, const u16* __restrict__ Kb, const u16* __restrict__ VTb,
    u16* __restrict__ Ob, unsigned* __restrict__ cnt) {
  __shared__ __align__(16) u16 Ks[2][64 * 64];
  __shared__ __align__(16) u16 Vt[2][64 * 64];
  __shared__ unsigned s_unit;
  for (;;) {
    if (threadIdx.x == 0) s_unit = atomicAdd(cnt, 1u);
    __syncthreads();
    unsigned u = s_unit;
    if (u >= 1024u) return;
    const int qb = 31 - (int)(u >> 5);   // longest-first
    const int bh = (int)(u & 31u);
    const size_t base = (size_t)bh * 2048 * 64;
    attn_one(Qb + base, Kb + base, VTb + base, Ob, bh >> 4, bh & 15, qb, Ks, Vt);
    __syncthreads();
  }
}

// ---------- launch ----------
extern "C" void kernel_launch(void* const* d_in, const int* in_sizes, int n_in,
                              void* d_out, int out_size, void* d_ws, size_t ws_size,
                              hipStream_t stream) {
  const float* x    = (const float*)d_in[0];   // [2,2048,1024]
  const float* wqkv = (const float*)d_in[1];   // [3072,1024]
  const float* bqkv = (const float*)d_in[2];   // [3072]
  const float* wo   = (const float*)d_in[3];   // [1024,1024]
  const float* bo   = (const float*)d_in[4];   // [1024]
  float* out = (float*)d_out;                  // [4096,1024] fp32

  const size_t MB = 1u << 20;
  char* ws = (char*)d_ws;
  u16* x_bf  = (u16*)(ws);             // 8 MB
  u16* wq_bf = (u16*)(ws + 8 * MB);    // 6 MB
  u16* wo_bf = (u16*)(ws + 14 * MB);   // 2 MB
  u16* q_buf = (u16*)(ws + 16 * MB);   // 8 MB  [B,nh,C,64]
  u16* k_buf = (u16*)(ws + 24 * MB);   // 8 MB  [B,nh,C,64]
  u16* vt_buf= (u16*)(ws + 32 * MB);   // 8 MB  [B,nh,64,C]  (transposed)
  u16* a_out = (u16*)(ws + 40 * MB);   // 8 MB  [4096,1024]

  // work-stealing counter: last 4 bytes of d_out (scratch until gemm_out
  // fully rewrites d_out afterwards); zeroed by gemm_qkv each launch.
  unsigned* cnt = (unsigned*)((char*)d_out + (size_t)out_size * 4 - 4);

  cast_bf16_kernel<<<4096, 256, 0, stream>>>(x, x_bf, 1048576);
  cast_bf16_kernel<<<3072, 256, 0, stream>>>(wqkv, wq_bf, 786432);
  cast_bf16_kernel<<<1024, 256, 0, stream>>>(wo, wo_bf, 262144);

  gemm_qkv_kernel<<<dim3(24, 32), 256, 0, stream>>>(x_bf, wq_bf, bqkv,
                                                    q_buf, k_buf, vt_buf, cnt);
  attn_kernel<<<1024, 128, 0, stream>>>(q_buf, k_buf, vt_buf, a_out, cnt);
  gemm_out_kernel<<<dim3(8, 32), 256, 0, stream>>>(a_out, wo_bf, bo, out);
}

// Round 8
// 168.230 us; speedup vs baseline: 1.1123x; 1.1123x over previous
//
#include <hip/hip_runtime.h>
#include <hip/hip_bf16.h>
#include <math.h>

typedef unsigned short u16;
typedef __attribute__((ext_vector_type(8))) __bf16 bf16x8;
typedef __attribute__((ext_vector_type(4))) float f32x4;
typedef __attribute__((ext_vector_type(8))) unsigned short u16x8;
typedef __attribute__((ext_vector_type(4))) unsigned int u32x4;

// ---------- helpers ----------
__device__ __forceinline__ u16 f2bf(float f) {
  union { float f; unsigned u; } x; x.f = f;
  unsigned r = x.u + 0x7fffu + ((x.u >> 16) & 1u);   // RNE
  return (u16)(r >> 16);
}

__device__ __forceinline__ void gload16(const u16* g, u16* l) {
  __builtin_amdgcn_global_load_lds(
      (const __attribute__((address_space(1))) void*)g,
      (__attribute__((address_space(3))) void*)l, 16, 0, 0);
}

#define MFMA16(a, b, c) __builtin_amdgcn_mfma_f32_16x16x32_bf16((a), (b), (c), 0, 0, 0)

// Q pre-scale: 1/sqrt(64) * log2(e)  (softmax done in exp2 domain)
#define QSCALE 0.18033688011112043f

// ---------- cast fp32 -> bf16 (vectorized) ----------
__global__ __launch_bounds__(256) void cast_bf16_kernel(
    const float* __restrict__ in, u16* __restrict__ out, int n4) {
  int i = blockIdx.x * 256 + threadIdx.x;
  if (i >= n4) return;
  f32x4 v = *(const f32x4*)(in + (size_t)i * 4);
  u16 o0 = f2bf(v[0]), o1 = f2bf(v[1]), o2 = f2bf(v[2]), o3 = f2bf(v[3]);
  unsigned lo = (unsigned)o0 | ((unsigned)o1 << 16);
  unsigned hi = (unsigned)o2 | ((unsigned)o3 << 16);
  ((unsigned*)out)[(size_t)i * 2] = lo;
  ((unsigned*)out)[(size_t)i * 2 + 1] = hi;
}

// ---------- shared 128x128 / BK=64 bf16 GEMM main loop (C = A * B^T) ----------
__device__ __forceinline__ void gemm_bt_128(
    const u16* __restrict__ A, const u16* __restrict__ B, int K, int m0, int n0,
    u16* As, u16* Bs, f32x4 acc[4][4]) {
  const int tid = threadIdx.x;
  const int lane = tid & 63;
  const int wr = tid >> 7;
  const int wc = (tid >> 6) & 1;
  for (int k0 = 0; k0 < K; k0 += 64) {
    #pragma unroll
    for (int it = 0; it < 4; ++it) {
      int c = it * 256 + tid;
      int row = c >> 3;
      int ko = (c & 7) << 3;
      gload16(A + (size_t)(m0 + row) * K + (k0 + ko), As + c * 8);
      gload16(B + (size_t)(n0 + row) * K + (k0 + ko), Bs + c * 8);
    }
    __syncthreads();
    #pragma unroll
    for (int kk = 0; kk < 2; ++kk) {
      bf16x8 a[4], b[4];
      #pragma unroll
      for (int m = 0; m < 4; ++m)
        a[m] = *(const bf16x8*)(As + ((wr * 64 + m * 16 + (lane & 15)) * 64 +
                                      kk * 32 + ((lane >> 4) << 3)));
      #pragma unroll
      for (int n = 0; n < 4; ++n)
        b[n] = *(const bf16x8*)(Bs + ((wc * 64 + n * 16 + (lane & 15)) * 64 +
                                      kk * 32 + ((lane >> 4) << 3)));
      #pragma unroll
      for (int m = 0; m < 4; ++m)
        #pragma unroll
        for (int n = 0; n < 4; ++n)
          acc[m][n] = MFMA16(a[m], b[n], acc[m][n]);
    }
    __syncthreads();
  }
}

// ---------- GEMM1: qkv = x @ Wqkv^T + b; Q,K per-head [q][d]; V per-head [d][q] ----------
__global__ __launch_bounds__(256) void gemm_qkv_kernel(
    const u16* __restrict__ X, const u16* __restrict__ W, const float* __restrict__ bias,
    u16* __restrict__ Qb, u16* __restrict__ Kb, u16* __restrict__ VTb,
    unsigned* __restrict__ cnt) {
  if (threadIdx.x == 0 && blockIdx.x == 0 && blockIdx.y == 0) *cnt = 0u;
  __shared__ __align__(16) u16 As[128 * 64];
  __shared__ __align__(16) u16 Bs[128 * 64];
  f32x4 acc[4][4];
  #pragma unroll
  for (int m = 0; m < 4; ++m)
    #pragma unroll
    for (int n = 0; n < 4; ++n) acc[m][n] = (f32x4){0.f, 0.f, 0.f, 0.f};
  const int m0 = blockIdx.y * 128;
  const int n0 = blockIdx.x * 128;
  gemm_bt_128(X, W, 1024, m0, n0, As, Bs, acc);
  const int lane = threadIdx.x & 63;
  const int wr = threadIdx.x >> 7, wc = (threadIdx.x >> 6) & 1;
  #pragma unroll
  for (int m = 0; m < 4; ++m) {
    #pragma unroll
    for (int n = 0; n < 4; ++n) {
      #pragma unroll
      for (int j = 0; j < 4; ++j) {
        int row = m0 + wr * 64 + m * 16 + ((lane >> 4) << 2) + j;
        int col = n0 + wc * 64 + n * 16 + (lane & 15);
        float v = acc[m][n][j] + bias[col];
        int which = col >> 10;
        int rem = col & 1023;
        int h = rem >> 6, d = rem & 63;
        int bb = row >> 11, q = row & 2047;
        int hh = bb * 16 + h;
        if (which == 0) {
          Qb[((size_t)hh * 2048 + q) * 64 + d] = f2bf(v * QSCALE);
        } else if (which == 1) {
          Kb[((size_t)hh * 2048 + q) * 64 + d] = f2bf(v);
        } else {
          VTb[((size_t)hh * 64 + d) * 2048 + q] = f2bf(v);   // transposed
        }
      }
    }
  }
}

// ---------- GEMM2: out = attn @ Wo^T + b (fp32 out) ----------
__global__ __launch_bounds__(256) void gemm_out_kernel(
    const u16* __restrict__ Ain, const u16* __restrict__ W, const float* __restrict__ bias,
    float* __restrict__ out) {
  __shared__ __align__(16) u16 As[128 * 64];
  __shared__ __align__(16) u16 Bs[128 * 64];
  f32x4 acc[4][4];
  #pragma unroll
  for (int m = 0; m < 4; ++m)
    #pragma unroll
    for (int n = 0; n < 4; ++n) acc[m][n] = (f32x4){0.f, 0.f, 0.f, 0.f};
  const int m0 = blockIdx.y * 128;
  const int n0 = blockIdx.x * 128;
  gemm_bt_128(Ain, W, 1024, m0, n0, As, Bs, acc);
  const int lane = threadIdx.x & 63;
  const int wr = threadIdx.x >> 7, wc = (threadIdx.x >> 6) & 1;
  #pragma unroll
  for (int m = 0; m < 4; ++m) {
    #pragma unroll
    for (int n = 0; n < 4; ++n) {
      #pragma unroll
      for (int j = 0; j < 4; ++j) {
        int row = m0 + wr * 64 + m * 16 + ((lane >> 4) << 2) + j;
        int col = n0 + wc * 64 + n * 16 + (lane & 15);
        out[(size_t)row * 1024 + col] = acc[m][n][j] + bias[col];
      }
    }
  }
}

// ---------- causal flash attention: swapped-QK^T, in-register softmax & P ----------
// Round-5-verified 4-wave body; V now staged via global_load_lds from V^T with
// pre-swizzled source (linear LDS dest, rule-21 compliant). exp2 domain.
__device__ __forceinline__ void attn_one(
    const u16* __restrict__ Qh, const u16* __restrict__ Kh, const u16* __restrict__ VTh,
    u16* __restrict__ Ob, int bb, int h, int qt,
    u16 (*Ks)[64 * 64], u16 (*Vt)[64 * 64]) {
  const int tid = threadIdx.x, lane = tid & 63, w = tid >> 6;
  const int g = lane >> 4, q15 = lane & 15;

  // Q fragment (B-operand): lane holds Q[qrow][kk*32 + 8g + i]
  bf16x8 qf[2];
  const int qrow = qt * 64 + w * 16 + q15;
  #pragma unroll
  for (int kk = 0; kk < 2; ++kk)
    qf[kk] = *(const bf16x8*)(Qh + (size_t)qrow * 64 + kk * 32 + g * 8);

  f32x4 acc_o[4];
  #pragma unroll
  for (int n = 0; n < 4; ++n) acc_o[n] = (f32x4){0.f, 0.f, 0.f, 0.f};
  float m_run = -INFINITY, l_run = 0.f;

  const int nt = qt + 1;

  auto stageK = [&](int t, int buf) {
    #pragma unroll
    for (int it = 0; it < 2; ++it) {
      int c = it * 256 + tid;
      int row = c >> 3, b8 = c & 7;
      gload16(Kh + (size_t)(t * 64 + row) * 64 + ((b8 ^ (row & 7)) << 3),
              Ks[buf] + c * 8);
    }
  };
  auto stageV = [&](int t, int buf) {
    #pragma unroll
    for (int it = 0; it < 2; ++it) {
      int c = it * 256 + tid;
      int d = c >> 3, b8 = c & 7;
      int fv = (d + (d >> 3)) & 7;
      gload16(VTh + (size_t)d * 2048 + t * 64 + ((b8 ^ fv) << 3),
              Vt[buf] + c * 8);
    }
  };

  // ---- prologue: tile 0 ----
  stageK(0, 0);
  stageV(0, 0);
  __syncthreads();

  for (int t = 0; t < nt; ++t) {
    const int cur = t & 1;
    if (t + 1 < nt) { stageK(t + 1, cur ^ 1); stageV(t + 1, cur ^ 1); }

    // ---- ST = K @ Q^T : lane holds P[q=q15][key = 16cb + 4g + j] ----
    f32x4 accs[4];
    __builtin_amdgcn_s_setprio(1);
    #pragma unroll
    for (int cb = 0; cb < 4; ++cb) {
      accs[cb] = (f32x4){0.f, 0.f, 0.f, 0.f};
      #pragma unroll
      for (int kk = 0; kk < 2; ++kk) {
        int row = cb * 16 + q15;
        int kblk = kk * 4 + g;
        bf16x8 kf = *(const bf16x8*)(Ks[cur] + row * 64 + ((kblk ^ (row & 7)) << 3));
        accs[cb] = MFMA16(kf, qf[kk], accs[cb]);
      }
    }
    __builtin_amdgcn_s_setprio(0);
    // causal mask on diagonal tile
    if (t == nt - 1) {
      #pragma unroll
      for (int cb = 0; cb < 4; ++cb)
        #pragma unroll
        for (int j = 0; j < 4; ++j) {
          int kg = t * 64 + cb * 16 + 4 * g + j;
          if (kg > qrow) accs[cb][j] = -INFINITY;
        }
    }

    // ---- online softmax (exp2 domain), lane-local q-row ----
    float mj = accs[0][0];
    #pragma unroll
    for (int cb = 0; cb < 4; ++cb)
      #pragma unroll
      for (int j = 0; j < 4; ++j) mj = fmaxf(mj, accs[cb][j]);
    mj = fmaxf(mj, __shfl_xor(mj, 16));
    mj = fmaxf(mj, __shfl_xor(mj, 32));
    float mn = fmaxf(m_run, mj);
    float sc = exp2f(m_run - mn);
    m_run = mn;
    float rs = 0.f;
    #pragma unroll
    for (int cb = 0; cb < 4; ++cb)
      #pragma unroll
      for (int j = 0; j < 4; ++j) {
        float p = exp2f(accs[cb][j] - mn);
        accs[cb][j] = p;
        rs += p;
      }
    rs += __shfl_xor(rs, 16);
    rs += __shfl_xor(rs, 32);
    l_run = l_run * sc + rs;

    // rescale acc_o (its rows live at q-local = 4g+j)
    float scj[4];
    #pragma unroll
    for (int j = 0; j < 4; ++j) scj[j] = __shfl(sc, 4 * g + j);
    #pragma unroll
    for (int n = 0; n < 4; ++n)
      #pragma unroll
      for (int j = 0; j < 4; ++j) acc_o[n][j] *= scj[j];

    // ---- pack P to bf16 pairs: Wp[cb][hh] = keys (16cb+4g+2hh, +1) ----
    unsigned Wp[4][2];
    #pragma unroll
    for (int cb = 0; cb < 4; ++cb)
      #pragma unroll
      for (int hh = 0; hh < 2; ++hh)
        asm("v_cvt_pk_bf16_f32 %0, %1, %2"
            : "=v"(Wp[cb][hh]) : "v"(accs[cb][2 * hh]), "v"(accs[cb][2 * hh + 1]));

    // ---- exchange into PV A-fragments: lane needs keys kk*32+8g..+7 ----
    unsigned aw[2][4];
    #pragma unroll
    for (int kk = 0; kk < 2; ++kk)
      #pragma unroll
      for (int iw = 0; iw < 4; ++iw) {
        int srcLane = q15 + ((((g & 1) << 1) + (iw >> 1)) << 4);
        unsigned c0 = __shfl(Wp[2 * kk + 0][iw & 1], srcLane);
        unsigned c1 = __shfl(Wp[2 * kk + 1][iw & 1], srcLane);
        aw[kk][iw] = (g >> 1) ? c1 : c0;
      }
    bf16x8 pa0 = __builtin_bit_cast(bf16x8, (u32x4){aw[0][0], aw[0][1], aw[0][2], aw[0][3]});
    bf16x8 pa1 = __builtin_bit_cast(bf16x8, (u32x4){aw[1][0], aw[1][1], aw[1][2], aw[1][3]});

    // ---- O += P @ V  (V via swizzled ds_read_b128) ----
    __builtin_amdgcn_s_setprio(1);
    #pragma unroll
    for (int n = 0; n < 4; ++n) {
      #pragma unroll
      for (int kk = 0; kk < 2; ++kk) {
        int cblk = kk * 4 + g;
        int d = n * 16 + q15;
        int fv = (d + (d >> 3)) & 7;
        bf16x8 vb = *(const bf16x8*)(Vt[cur] + d * 64 + ((cblk ^ fv) << 3));
        acc_o[n] = MFMA16(kk ? pa1 : pa0, vb, acc_o[n]);
      }
    }
    __builtin_amdgcn_s_setprio(0);
    __syncthreads();
  }

  // ---- epilogue: O /= l, write bf16 to [B*C, H] ----
  float invl = 1.0f / l_run;
  float invj[4];
  #pragma unroll
  for (int j = 0; j < 4; ++j) invj[j] = __shfl(invl, 4 * g + j);
  #pragma unroll
  for (int n = 0; n < 4; ++n)
    #pragma unroll
    for (int j = 0; j < 4; ++j) {
      int qg = qt * 64 + w * 16 + 4 * g + j;
      Ob[((size_t)(bb * 2048 + qg)) * 1024 + h * 64 + n * 16 + q15] =
          f2bf(acc_o[n][j] * invj[j]);
    }
}

// Persistent work-stealing: 1024 units (head, qt), longest-first (LPT).
// grid 768 < units so stealing actually balances; 3 blocks/CU x 4 waves.
__global__ __launch_bounds__(256, 3) void attn_kernel(
    const u16* __restrict__ Qb, const u16* __restrict__ Kb, const u16* __restrict__ VTb,
    u16* __restrict__ Ob, unsigned* __restrict__ cnt) {
  __shared__ __align__(16) u16 Ks[2][64 * 64];
  __shared__ __align__(16) u16 Vt[2][64 * 64];
  __shared__ unsigned s_unit;
  for (;;) {
    if (threadIdx.x == 0) s_unit = atomicAdd(cnt, 1u);
    __syncthreads();
    unsigned u = s_unit;
    if (u >= 1024u) return;
    const int qt = 31 - (int)(u >> 5);   // longest-first
    const int bh = (int)(u & 31u);
    const size_t base = (size_t)bh * 2048 * 64;   // same for K and V^T
    attn_one(Qb + base, Kb + base, VTb + base, Ob, bh >> 4, bh & 15, qt, Ks, Vt);
    __syncthreads();
  }
}

// ---------- launch ----------
extern "C" void kernel_launch(void* const* d_in, const int* in_sizes, int n_in,
                              void* d_out, int out_size, void* d_ws, size_t ws_size,
                              hipStream_t stream) {
  const float* x    = (const float*)d_in[0];   // [2,2048,1024]
  const float* wqkv = (const float*)d_in[1];   // [3072,1024]
  const float* bqkv = (const float*)d_in[2];   // [3072]
  const float* wo   = (const float*)d_in[3];   // [1024,1024]
  const float* bo   = (const float*)d_in[4];   // [1024]
  float* out = (float*)d_out;                  // [4096,1024] fp32

  const size_t MB = 1u << 20;
  char* ws = (char*)d_ws;
  u16* x_bf  = (u16*)(ws);             // 8 MB
  u16* wq_bf = (u16*)(ws + 8 * MB);    // 6 MB
  u16* wo_bf = (u16*)(ws + 14 * MB);   // 2 MB
  u16* q_buf = (u16*)(ws + 16 * MB);   // 8 MB  [B,nh,C,64]
  u16* k_buf = (u16*)(ws + 24 * MB);   // 8 MB  [B,nh,C,64]
  u16* vt_buf= (u16*)(ws + 32 * MB);   // 8 MB  [B,nh,64,C]  (transposed)
  u16* a_out = (u16*)(ws + 40 * MB);   // 8 MB  [4096,1024]

  // work-stealing counter: last 4 bytes of d_out (scratch until gemm_out
  // fully rewrites d_out afterwards); zeroed by gemm_qkv each launch.
  unsigned* cnt = (unsigned*)((char*)d_out + (size_t)out_size * 4 - 4);

  cast_bf16_kernel<<<4096, 256, 0, stream>>>(x, x_bf, 1048576);
  cast_bf16_kernel<<<3072, 256, 0, stream>>>(wqkv, wq_bf, 786432);
  cast_bf16_kernel<<<1024, 256, 0, stream>>>(wo, wo_bf, 262144);

  gemm_qkv_kernel<<<dim3(24, 32), 256, 0, stream>>>(x_bf, wq_bf, bqkv,
                                                    q_buf, k_buf, vt_buf, cnt);
  attn_kernel<<<768, 256, 0, stream>>>(q_buf, k_buf, vt_buf, a_out, cnt);
  gemm_out_kernel<<<dim3(8, 32), 256, 0, stream>>>(a_out, wo_bf, bo, out);
}

// Round 9
// 151.429 us; speedup vs baseline: 1.2357x; 1.1110x over previous
//
#include <hip/hip_runtime.h>
#include <hip/hip_bf16.h>
#include <math.h>

typedef unsigned short u16;
typedef __attribute__((ext_vector_type(8))) __bf16 bf16x8;
typedef __attribute__((ext_vector_type(4))) float f32x4;
typedef __attribute__((ext_vector_type(8))) unsigned short u16x8;
typedef __attribute__((ext_vector_type(4))) unsigned int u32x4;

// ---------- helpers ----------
__device__ __forceinline__ u16 f2bf(float f) {
  union { float f; unsigned u; } x; x.f = f;
  unsigned r = x.u + 0x7fffu + ((x.u >> 16) & 1u);   // RNE
  return (u16)(r >> 16);
}

__device__ __forceinline__ void gload16(const u16* g, u16* l) {
  __builtin_amdgcn_global_load_lds(
      (const __attribute__((address_space(1))) void*)g,
      (__attribute__((address_space(3))) void*)l, 16, 0, 0);
}

#define MFMA16(a, b, c) __builtin_amdgcn_mfma_f32_16x16x32_bf16((a), (b), (c), 0, 0, 0)

// Q pre-scale: 1/sqrt(64) * log2(e)  (softmax done in exp2 domain)
#define QSCALE 0.18033688011112043f

// ---------- merged cast fp32 -> bf16 (x, Wqkv, Wo in one launch) ----------
__global__ __launch_bounds__(256) void cast_all_kernel(
    const float* __restrict__ x, const float* __restrict__ wqkv,
    const float* __restrict__ wo, u16* __restrict__ xb,
    u16* __restrict__ wqb, u16* __restrict__ wob) {
  int i = blockIdx.x * 256 + threadIdx.x;   // in float4 units
  const float* src; u16* dst;
  if (i < 1048576)      { src = x;    dst = xb;  }
  else if (i < 1835008) { src = wqkv; dst = wqb; i -= 1048576; }
  else                  { src = wo;   dst = wob; i -= 1835008; }
  f32x4 v = *(const f32x4*)(src + (size_t)i * 4);
  u16 o0 = f2bf(v[0]), o1 = f2bf(v[1]), o2 = f2bf(v[2]), o3 = f2bf(v[3]);
  unsigned lo = (unsigned)o0 | ((unsigned)o1 << 16);
  unsigned hi = (unsigned)o2 | ((unsigned)o3 << 16);
  ((unsigned*)dst)[(size_t)i * 2] = lo;
  ((unsigned*)dst)[(size_t)i * 2 + 1] = hi;
}

// ---------- shared 128x128 / BK=64 bf16 GEMM main loop (C = A * B^T) ----------
__device__ __forceinline__ void gemm_bt_128(
    const u16* __restrict__ A, const u16* __restrict__ B, int K, int m0, int n0,
    u16* As, u16* Bs, f32x4 acc[4][4]) {
  const int tid = threadIdx.x;
  const int lane = tid & 63;
  const int wr = tid >> 7;
  const int wc = (tid >> 6) & 1;
  for (int k0 = 0; k0 < K; k0 += 64) {
    #pragma unroll
    for (int it = 0; it < 4; ++it) {
      int c = it * 256 + tid;
      int row = c >> 3;
      int ko = (c & 7) << 3;
      gload16(A + (size_t)(m0 + row) * K + (k0 + ko), As + c * 8);
      gload16(B + (size_t)(n0 + row) * K + (k0 + ko), Bs + c * 8);
    }
    __syncthreads();
    #pragma unroll
    for (int kk = 0; kk < 2; ++kk) {
      bf16x8 a[4], b[4];
      #pragma unroll
      for (int m = 0; m < 4; ++m)
        a[m] = *(const bf16x8*)(As + ((wr * 64 + m * 16 + (lane & 15)) * 64 +
                                      kk * 32 + ((lane >> 4) << 3)));
      #pragma unroll
      for (int n = 0; n < 4; ++n)
        b[n] = *(const bf16x8*)(Bs + ((wc * 64 + n * 16 + (lane & 15)) * 64 +
                                      kk * 32 + ((lane >> 4) << 3)));
      #pragma unroll
      for (int m = 0; m < 4; ++m)
        #pragma unroll
        for (int n = 0; n < 4; ++n)
          acc[m][n] = MFMA16(a[m], b[n], acc[m][n]);
    }
    __syncthreads();
  }
}

// ---------- GEMM1: qkv = x @ Wqkv^T + b, scatter q/k/v to [B,nh,C,64] bf16 ----------
__global__ __launch_bounds__(256) void gemm_qkv_kernel(
    const u16* __restrict__ X, const u16* __restrict__ W, const float* __restrict__ bias,
    u16* __restrict__ Qb, u16* __restrict__ Kb, u16* __restrict__ Vb) {
  __shared__ __align__(16) u16 As[128 * 64];
  __shared__ __align__(16) u16 Bs[128 * 64];
  f32x4 acc[4][4];
  #pragma unroll
  for (int m = 0; m < 4; ++m)
    #pragma unroll
    for (int n = 0; n < 4; ++n) acc[m][n] = (f32x4){0.f, 0.f, 0.f, 0.f};
  const int m0 = blockIdx.y * 128;
  const int n0 = blockIdx.x * 128;
  gemm_bt_128(X, W, 1024, m0, n0, As, Bs, acc);
  const int lane = threadIdx.x & 63;
  const int wr = threadIdx.x >> 7, wc = (threadIdx.x >> 6) & 1;
  #pragma unroll
  for (int m = 0; m < 4; ++m) {
    #pragma unroll
    for (int n = 0; n < 4; ++n) {
      #pragma unroll
      for (int j = 0; j < 4; ++j) {
        int row = m0 + wr * 64 + m * 16 + ((lane >> 4) << 2) + j;
        int col = n0 + wc * 64 + n * 16 + (lane & 15);
        float v = acc[m][n][j] + bias[col];
        int which = col >> 10;
        int rem = col & 1023;
        int h = rem >> 6, d = rem & 63;
        int bb = row >> 11, q = row & 2047;
        if (which == 0) v *= QSCALE;  // Q pre-scale (exp2-domain softmax)
        u16* dst = (which == 0) ? Qb : (which == 1 ? Kb : Vb);
        dst[((size_t)((bb * 16 + h) * 2048 + q)) * 64 + d] = f2bf(v);
      }
    }
  }
}

// ---------- GEMM2: out = attn @ Wo^T + b (fp32 out), 64x128 tile ----------
__global__ __launch_bounds__(256) void gemm_out_kernel(
    const u16* __restrict__ Ain, const u16* __restrict__ W, const float* __restrict__ bias,
    float* __restrict__ out) {
  __shared__ __align__(16) u16 As[64 * 64];
  __shared__ __align__(16) u16 Bs[128 * 64];
  const int tid = threadIdx.x;
  const int lane = tid & 63;
  const int wc = tid >> 6;                 // wave -> 32-col group
  const int m0 = blockIdx.y * 64;
  const int n0 = blockIdx.x * 128;
  f32x4 acc[4][2] = {};
  for (int k0 = 0; k0 < 1024; k0 += 64) {
    #pragma unroll
    for (int it = 0; it < 2; ++it) {
      int c = it * 256 + tid;
      gload16(Ain + (size_t)(m0 + (c >> 3)) * 1024 + k0 + ((c & 7) << 3), As + c * 8);
    }
    #pragma unroll
    for (int it = 0; it < 4; ++it) {
      int c = it * 256 + tid;
      gload16(W + (size_t)(n0 + (c >> 3)) * 1024 + k0 + ((c & 7) << 3), Bs + c * 8);
    }
    __syncthreads();
    #pragma unroll
    for (int kk = 0; kk < 2; ++kk) {
      bf16x8 a[4], b[2];
      #pragma unroll
      for (int m = 0; m < 4; ++m)
        a[m] = *(const bf16x8*)(As + ((m * 16 + (lane & 15)) * 64 +
                                      kk * 32 + ((lane >> 4) << 3)));
      #pragma unroll
      for (int n = 0; n < 2; ++n)
        b[n] = *(const bf16x8*)(Bs + ((wc * 32 + n * 16 + (lane & 15)) * 64 +
                                      kk * 32 + ((lane >> 4) << 3)));
      #pragma unroll
      for (int m = 0; m < 4; ++m)
        #pragma unroll
        for (int n = 0; n < 2; ++n)
          acc[m][n] = MFMA16(a[m], b[n], acc[m][n]);
    }
    __syncthreads();
  }
  #pragma unroll
  for (int m = 0; m < 4; ++m)
    #pragma unroll
    for (int n = 0; n < 2; ++n)
      #pragma unroll
      for (int j = 0; j < 4; ++j) {
        int row = m0 + m * 16 + ((lane >> 4) << 2) + j;
        int col = n0 + wc * 32 + n * 16 + (lane & 15);
        out[(size_t)row * 1024 + col] = acc[m][n][j] + bias[col];
      }
}

// ---------- causal flash attention: swapped-QK^T, in-register softmax & P ----------
// Round-5-verified body (best measured: 68.6 us), exp2 domain.
__device__ __forceinline__ void attn_one(
    const u16* __restrict__ Qh, const u16* __restrict__ Kh, const u16* __restrict__ Vh,
    u16* __restrict__ Ob, int bb, int h, int qt,
    u16 (*Ks)[64 * 64], u16 (*Vt)[64 * 64]) {
  const int tid = threadIdx.x, lane = tid & 63, w = tid >> 6;
  const int g = lane >> 4, q15 = lane & 15;

  // Q fragment (B-operand): lane holds Q[qrow][kk*32 + 8g + i]
  bf16x8 qf[2];
  const int qrow = qt * 64 + w * 16 + q15;
  #pragma unroll
  for (int kk = 0; kk < 2; ++kk)
    qf[kk] = *(const bf16x8*)(Qh + (size_t)qrow * 64 + kk * 32 + g * 8);

  f32x4 acc_o[4];
  #pragma unroll
  for (int n = 0; n < 4; ++n) acc_o[n] = (f32x4){0.f, 0.f, 0.f, 0.f};
  float m_run = -INFINITY, l_run = 0.f;

  const int nt = qt + 1;

  auto stageK = [&](int t, int buf) {
    #pragma unroll
    for (int it = 0; it < 2; ++it) {
      int c = it * 256 + tid;
      int row = c >> 3, b8 = c & 7;
      gload16(Kh + (size_t)(t * 64 + row) * 64 + ((b8 ^ (row & 7)) << 3),
              Ks[buf] + c * 8);
    }
  };

  // ---- prologue: tile 0 ----
  stageK(0, 0);
  #pragma unroll
  for (int it = 0; it < 2; ++it) {
    int kloc = it * 32 + (tid >> 3);
    int d0 = (tid & 7) << 3;
    u16x8 v = *(const u16x8*)(Vh + (size_t)kloc * 64 + d0);
    #pragma unroll
    for (int i = 0; i < 8; ++i) {
      int d = d0 + i;
      int fv = (d + (d >> 3)) & 7;
      Vt[0][d * 64 + (((kloc >> 3) ^ fv) << 3) + (kloc & 7)] = v[i];
    }
  }
  __syncthreads();

  for (int t = 0; t < nt; ++t) {
    const int cur = t & 1;
    const bool pre = (t + 1 < nt);
    u16x8 vreg[2];
    if (pre) {
      stageK(t + 1, cur ^ 1);
      #pragma unroll
      for (int it = 0; it < 2; ++it) {
        int kloc = it * 32 + (tid >> 3);
        int d0 = (tid & 7) << 3;
        vreg[it] = *(const u16x8*)(Vh + (size_t)((t + 1) * 64 + kloc) * 64 + d0);
      }
    }

    // ---- ST = K @ Q^T : lane holds P[q=q15][key = 16cb + 4g + j] ----
    f32x4 accs[4];
    __builtin_amdgcn_s_setprio(1);
    #pragma unroll
    for (int cb = 0; cb < 4; ++cb) {
      accs[cb] = (f32x4){0.f, 0.f, 0.f, 0.f};
      #pragma unroll
      for (int kk = 0; kk < 2; ++kk) {
        int row = cb * 16 + q15;
        int kblk = kk * 4 + g;
        bf16x8 kf = *(const bf16x8*)(Ks[cur] + row * 64 + ((kblk ^ (row & 7)) << 3));
        accs[cb] = MFMA16(kf, qf[kk], accs[cb]);
      }
    }
    __builtin_amdgcn_s_setprio(0);
    // causal mask on diagonal tile
    if (t == nt - 1) {
      #pragma unroll
      for (int cb = 0; cb < 4; ++cb)
        #pragma unroll
        for (int j = 0; j < 4; ++j) {
          int kg = t * 64 + cb * 16 + 4 * g + j;
          if (kg > qrow) accs[cb][j] = -INFINITY;
        }
    }

    // ---- online softmax (exp2 domain), lane-local q-row ----
    float mj = accs[0][0];
    #pragma unroll
    for (int cb = 0; cb < 4; ++cb)
      #pragma unroll
      for (int j = 0; j < 4; ++j) mj = fmaxf(mj, accs[cb][j]);
    mj = fmaxf(mj, __shfl_xor(mj, 16));
    mj = fmaxf(mj, __shfl_xor(mj, 32));
    float mn = fmaxf(m_run, mj);
    float sc = exp2f(m_run - mn);
    m_run = mn;
    float rs = 0.f;
    #pragma unroll
    for (int cb = 0; cb < 4; ++cb)
      #pragma unroll
      for (int j = 0; j < 4; ++j) {
        float p = exp2f(accs[cb][j] - mn);
        accs[cb][j] = p;
        rs += p;
      }
    rs += __shfl_xor(rs, 16);
    rs += __shfl_xor(rs, 32);
    l_run = l_run * sc + rs;

    // rescale acc_o (its rows live at q-local = 4g+j)
    float scj[4];
    #pragma unroll
    for (int j = 0; j < 4; ++j) scj[j] = __shfl(sc, 4 * g + j);
    #pragma unroll
    for (int n = 0; n < 4; ++n)
      #pragma unroll
      for (int j = 0; j < 4; ++j) acc_o[n][j] *= scj[j];

    // ---- pack P to bf16 pairs: Wp[cb][hh] = keys (16cb+4g+2hh, +1) ----
    unsigned Wp[4][2];
    #pragma unroll
    for (int cb = 0; cb < 4; ++cb)
      #pragma unroll
      for (int hh = 0; hh < 2; ++hh)
        asm("v_cvt_pk_bf16_f32 %0, %1, %2"
            : "=v"(Wp[cb][hh]) : "v"(accs[cb][2 * hh]), "v"(accs[cb][2 * hh + 1]));

    // ---- exchange into PV A-fragments: lane needs keys kk*32+8g..+7 ----
    unsigned aw[2][4];
    #pragma unroll
    for (int kk = 0; kk < 2; ++kk)
      #pragma unroll
      for (int iw = 0; iw < 4; ++iw) {
        int srcLane = q15 + ((((g & 1) << 1) + (iw >> 1)) << 4);
        unsigned c0 = __shfl(Wp[2 * kk + 0][iw & 1], srcLane);
        unsigned c1 = __shfl(Wp[2 * kk + 1][iw & 1], srcLane);
        aw[kk][iw] = (g >> 1) ? c1 : c0;
      }
    bf16x8 pa0 = __builtin_bit_cast(bf16x8, (u32x4){aw[0][0], aw[0][1], aw[0][2], aw[0][3]});
    bf16x8 pa1 = __builtin_bit_cast(bf16x8, (u32x4){aw[1][0], aw[1][1], aw[1][2], aw[1][3]});

    // ---- O += P @ V  (V via swizzled ds_read_b128) ----
    __builtin_amdgcn_s_setprio(1);
    #pragma unroll
    for (int n = 0; n < 4; ++n) {
      #pragma unroll
      for (int kk = 0; kk < 2; ++kk) {
        int cblk = kk * 4 + g;
        int d = n * 16 + q15;
        int fv = (d + (d >> 3)) & 7;
        bf16x8 vb = *(const bf16x8*)(Vt[cur] + d * 64 + ((cblk ^ fv) << 3));
        acc_o[n] = MFMA16(kk ? pa1 : pa0, vb, acc_o[n]);
      }
    }
    __builtin_amdgcn_s_setprio(0);

    if (pre) {
      // write-late: V regs -> LDS (swizzled) after compute
      #pragma unroll
      for (int it = 0; it < 2; ++it) {
        int kloc = it * 32 + (tid >> 3);
        int d0 = (tid & 7) << 3;
        #pragma unroll
        for (int i = 0; i < 8; ++i) {
          int d = d0 + i;
          int fv = (d + (d >> 3)) & 7;
          Vt[cur ^ 1][d * 64 + (((kloc >> 3) ^ fv) << 3) + (kloc & 7)] = vreg[it][i];
        }
      }
    }
    __syncthreads();
  }

  // ---- epilogue: O /= l, write bf16 to [B*C, H] ----
  float invl = 1.0f / l_run;
  float invj[4];
  #pragma unroll
  for (int j = 0; j < 4; ++j) invj[j] = __shfl(invl, 4 * g + j);
  #pragma unroll
  for (int n = 0; n < 4; ++n)
    #pragma unroll
    for (int j = 0; j < 4; ++j) {
      int qg = qt * 64 + w * 16 + 4 * g + j;
      Ob[((size_t)(bb * 2048 + qg)) * 1024 + h * 64 + n * 16 + q15] =
          f2bf(acc_o[n][j] * invj[j]);
    }
}

// grid = 32 heads x 16 balanced pairs; block handles q-tiles (31-p, p): 33 KV tiles.
__global__ __launch_bounds__(256, 4) void attn_kernel(
    const u16* __restrict__ Qb, const u16* __restrict__ Kb, const u16* __restrict__ Vb,
    u16* __restrict__ Ob) {
  __shared__ __align__(16) u16 Ks[2][64 * 64];
  __shared__ __align__(16) u16 Vt[2][64 * 64];
  const int blk = blockIdx.x;
  const int p = blk & 15;
  const int bh = blk >> 4;             // 0..31 (b*16+h)
  const size_t base = (size_t)bh * 2048 * 64;
  const int bb = bh >> 4, h = bh & 15;
  attn_one(Qb + base, Kb + base, Vb + base, Ob, bb, h, 31 - p, Ks, Vt);
  attn_one(Qb + base, Kb + base, Vb + base, Ob, bb, h, p, Ks, Vt);
}

// ---------- launch ----------
extern "C" void kernel_launch(void* const* d_in, const int* in_sizes, int n_in,
                              void* d_out, int out_size, void* d_ws, size_t ws_size,
                              hipStream_t stream) {
  const float* x    = (const float*)d_in[0];   // [2,2048,1024]
  const float* wqkv = (const float*)d_in[1];   // [3072,1024]
  const float* bqkv = (const float*)d_in[2];   // [3072]
  const float* wo   = (const float*)d_in[3];   // [1024,1024]
  const float* bo   = (const float*)d_in[4];   // [1024]
  float* out = (float*)d_out;                  // [4096,1024] fp32

  const size_t MB = 1u << 20;
  char* ws = (char*)d_ws;
  u16* x_bf  = (u16*)(ws);             // 8 MB
  u16* wq_bf = (u16*)(ws + 8 * MB);    // 6 MB
  u16* wo_bf = (u16*)(ws + 14 * MB);   // 2 MB
  u16* q_buf = (u16*)(ws + 16 * MB);   // 8 MB  [B,nh,C,64]
  u16* k_buf = (u16*)(ws + 24 * MB);   // 8 MB
  u16* v_buf = (u16*)(ws + 32 * MB);   // 8 MB
  u16* a_out = (u16*)(ws + 40 * MB);   // 8 MB  [4096,1024]

  cast_all_kernel<<<8192, 256, 0, stream>>>(x, wqkv, wo, x_bf, wq_bf, wo_bf);

  gemm_qkv_kernel<<<dim3(24, 32), 256, 0, stream>>>(x_bf, wq_bf, bqkv,
                                                    q_buf, k_buf, v_buf);
  attn_kernel<<<512, 256, 0, stream>>>(q_buf, k_buf, v_buf, a_out);
  gemm_out_kernel<<<dim3(8, 64), 256, 0, stream>>>(a_out, wo_bf, bo, out);
}